// Round 20
// baseline (710.276 us; speedup 1.0000x reference)
//
#include <hip/hip_runtime.h>
#include <math.h>

constexpr int K_IN  = 1433;
constexpr int HID   = 16;
constexpr int NCLS  = 7;
constexpr int BLK   = 256;
constexpr int NB    = 256;   // coarse buckets: bucket = col >> 9
constexpr int NBLKA = 1024;  // pass-A blocks

__device__ inline float4 wave_reduce4(float4 v) {
#pragma unroll
  for (int off = 32; off > 0; off >>= 1) {
    v.x += __shfl_xor(v.x, off);
    v.y += __shfl_xor(v.y, off);
    v.z += __shfl_xor(v.z, off);
    v.w += __shfl_xor(v.w, off);
  }
  return v;
}

// exclusive scan over 256 values held one-per-thread (256-thread block)
__device__ inline int block_excl_scan256(int v, int* wsum) {
  const int lane = threadIdx.x & 63, wid = threadIdx.x >> 6;
  int s = v;
#pragma unroll
  for (int off = 1; off < 64; off <<= 1) {
    int t = __shfl_up(s, off);
    if (lane >= off) s += t;
  }
  if (lane == 63) wsum[wid] = s;
  __syncthreads();
  int woff = 0;
#pragma unroll
  for (int k = 0; k < 4; ++k) woff += (k < wid) ? wsum[k] : 0;
  return woff + s - v;
}

// ---- atomic-free CSR build (two-level LDS-histogram counting sort) -----

__global__ __launch_bounds__(256) void k_histA(const int* __restrict__ col,
                                               int* __restrict__ gHist, int nE) {
  __shared__ int h[NB];
  h[threadIdx.x] = 0;
  __syncthreads();
  const int ch = (nE + NBLKA - 1) / NBLKA;
  const int e0 = blockIdx.x * ch;
  const int e1 = min(e0 + ch, nE);
  for (int e = e0 + threadIdx.x; e < e1; e += 256) atomicAdd(&h[col[e] >> 9], 1);
  __syncthreads();
  gHist[threadIdx.x * NBLKA + blockIdx.x] = h[threadIdx.x];  // bucket-major
}

__global__ __launch_bounds__(256) void k_scanA(int* __restrict__ gHist,
                                               int* __restrict__ bTot) {
  __shared__ int wsum[4];
  const int b = blockIdx.x, t = threadIdx.x;
  int4* p = (int4*)(gHist + (size_t)b * NBLKA);
  int4 c = p[t];
  const int tsum = c.x + c.y + c.z + c.w;
  const int base = block_excl_scan256(tsum, wsum);
  int4 o; o.x = base; o.y = base + c.x; o.z = o.y + c.y; o.w = o.z + c.z;
  p[t] = o;
  if (t == 255) bTot[b] = base + tsum;
}

__global__ __launch_bounds__(256) void k_placeA(const int* __restrict__ row,
                                                const int* __restrict__ col,
                                                const int* __restrict__ gHist,
                                                const int* __restrict__ bTot,
                                                int* __restrict__ sorted, int nE) {
  __shared__ int cur[NB];
  __shared__ int wsum[4];
  const int t = threadIdx.x;
  const int excl = block_excl_scan256(bTot[t], wsum);   // bBase on the fly
  cur[t] = excl + gHist[t * NBLKA + blockIdx.x];
  __syncthreads();
  const int ch = (nE + NBLKA - 1) / NBLKA;
  const int e0 = blockIdx.x * ch;
  const int e1 = min(e0 + ch, nE);
  for (int e = e0 + t; e < e1; e += 256) {
    const int c = col[e];
    const int p = atomicAdd(&cur[c >> 9], 1);           // LDS atomic
    sorted[p] = ((c & 511) << 17) | row[e];             // 26-bit pack
  }
}

__global__ __launch_bounds__(256) void k_bucketB(const int* __restrict__ sorted,
                                                 const int* __restrict__ bTot,
                                                 int* __restrict__ cnt,
                                                 int* __restrict__ start,
                                                 float* __restrict__ dinv,
                                                 int* __restrict__ rows, int n) {
  __shared__ int h[512];
  __shared__ int ls[512];
  __shared__ int sBase[NB];
  __shared__ int wsum[4];
  const int b = blockIdx.x, t = threadIdx.x;
  const int lane = t & 63, wid = t >> 6;
  h[t] = 0; h[t + 256] = 0;
  sBase[t] = block_excl_scan256(bTot[t], wsum);         // bBase on the fly
  __syncthreads();
  const int s0 = sBase[b];
  const int s1 = (b < 255) ? sBase[b + 1] : s0 + bTot[b];
  for (int e = s0 + t; e < s1; e += 256) atomicAdd(&h[(sorted[e] >> 17) & 511], 1);
  __syncthreads();
  const int c0 = h[2 * t], c1 = h[2 * t + 1];
  const int tsum = c0 + c1;
  int s = tsum;
#pragma unroll
  for (int off = 1; off < 64; off <<= 1) { int v = __shfl_up(s, off); if (lane >= off) s += v; }
  if (lane == 63) wsum[wid] = s;
  __syncthreads();
  int woff = 0;
#pragma unroll
  for (int k = 0; k < 4; ++k) woff += (k < wid) ? wsum[k] : 0;
  const int base = woff + s - tsum;
  ls[2 * t] = base;
  ls[2 * t + 1] = base + c0;
  const int gc0 = b * 512 + 2 * t;
  if (gc0 < n) {
    cnt[gc0] = c0; start[gc0] = s0 + base;
    dinv[gc0] = rsqrtf((float)(c0 + 1));
  }
  if (gc0 + 1 < n) {
    cnt[gc0 + 1] = c1; start[gc0 + 1] = s0 + base + c0;
    dinv[gc0 + 1] = rsqrtf((float)(c1 + 1));
  }
  __syncthreads();
  for (int e = s0 + t; e < s1; e += 256) {
    const int rc = sorted[e];
    const int p = atomicAdd(&ls[(rc >> 17) & 511], 1);  // LDS cursor
    rows[s0 + p] = rc & 0x1FFFF;
  }
}

// ---- layer compute -----------------------------------------------------

#define FMA_ROW(J, XS, W0, W1_, W2, W3) \
  acc[J][0]  = fmaf((XS), (W0).x,  acc[J][0]);  \
  acc[J][1]  = fmaf((XS), (W0).y,  acc[J][1]);  \
  acc[J][2]  = fmaf((XS), (W0).z,  acc[J][2]);  \
  acc[J][3]  = fmaf((XS), (W0).w,  acc[J][3]);  \
  acc[J][4]  = fmaf((XS), (W1_).x, acc[J][4]);  \
  acc[J][5]  = fmaf((XS), (W1_).y, acc[J][5]);  \
  acc[J][6]  = fmaf((XS), (W1_).z, acc[J][6]);  \
  acc[J][7]  = fmaf((XS), (W1_).w, acc[J][7]);  \
  acc[J][8]  = fmaf((XS), (W2).x,  acc[J][8]);  \
  acc[J][9]  = fmaf((XS), (W2).y,  acc[J][9]);  \
  acc[J][10] = fmaf((XS), (W2).z,  acc[J][10]); \
  acc[J][11] = fmaf((XS), (W2).w,  acc[J][11]); \
  acc[J][12] = fmaf((XS), (W3).x,  acc[J][12]); \
  acc[J][13] = fmaf((XS), (W3).y,  acc[J][13]); \
  acc[J][14] = fmaf((XS), (W3).z,  acc[J][14]); \
  acc[J][15] = fmaf((XS), (W3).w,  acc[J][15]);

// h1s = dinv * (x @ W1 + b1). v11: register-W + float4-x, 8 rows/wave.
// Lane owns 4 consecutive k per 256-chunk: 8 x-float4 + 16 W-float4 loads
// feed 512 FMAs (21 FMA/load, 2x v10). No LDS, no barriers.
__global__ __launch_bounds__(BLK) void k_gemm1(const float* __restrict__ x,
                                               const float* __restrict__ W1,
                                               const float* __restrict__ b1,
                                               const float* __restrict__ dinv,
                                               float* __restrict__ h1s, int n) {
  const int lane = threadIdx.x & 63;
  const int wave = threadIdx.x >> 6;
  const int r0 = blockIdx.x * 32 + wave * 8;
  bool vr[8];
  const float* xr[8];
#pragma unroll
  for (int j = 0; j < 8; ++j) {
    vr[j] = (r0 + j) < n;
    xr[j] = x + (size_t)(vr[j] ? r0 + j : 0) * K_IN;   // clamp, masked below
  }
  float acc[8][HID] = {};

  // 5 full 256-k chunks (k < 1280)
#pragma unroll 1
  for (int c = 0; c < 5; ++c) {
    const int k = c * 256 + lane * 4;
    float4 xq[8];
#pragma unroll
    for (int j = 0; j < 8; ++j)
      xq[j] = vr[j] ? *(const float4*)(xr[j] + k)
                    : make_float4(0.f, 0.f, 0.f, 0.f);
    const float4* wp = (const float4*)(W1 + (size_t)k * HID);
    {  // sub-k 0: W row k
      const float4 w0 = wp[0], w1 = wp[1], w2 = wp[2], w3 = wp[3];
#pragma unroll
      for (int j = 0; j < 8; ++j) { FMA_ROW(j, xq[j].x, w0, w1, w2, w3) }
    }
    {  // sub-k 1: W row k+1
      const float4 w0 = wp[4], w1 = wp[5], w2 = wp[6], w3 = wp[7];
#pragma unroll
      for (int j = 0; j < 8; ++j) { FMA_ROW(j, xq[j].y, w0, w1, w2, w3) }
    }
    {  // sub-k 2: W row k+2
      const float4 w0 = wp[8], w1 = wp[9], w2 = wp[10], w3 = wp[11];
#pragma unroll
      for (int j = 0; j < 8; ++j) { FMA_ROW(j, xq[j].z, w0, w1, w2, w3) }
    }
    {  // sub-k 3: W row k+3
      const float4 w0 = wp[12], w1 = wp[13], w2 = wp[14], w3 = wp[15];
#pragma unroll
      for (int j = 0; j < 8; ++j) { FMA_ROW(j, xq[j].w, w0, w1, w2, w3) }
    }
  }

  // tail chunk: k in [1280, 1433)
  {
    const int kbase = 1280 + lane * 4;
#pragma unroll
    for (int i = 0; i < 4; ++i) {
      const int k = kbase + i;
      if (k < K_IN) {
        const float4* wp = (const float4*)(W1 + (size_t)k * HID);
        const float4 w0 = wp[0], w1 = wp[1], w2 = wp[2], w3 = wp[3];
#pragma unroll
        for (int j = 0; j < 8; ++j) {
          const float xs = vr[j] ? xr[j][k] : 0.0f;
          FMA_ROW(j, xs, w0, w1, w2, w3)
        }
      }
    }
  }

  const float4* b14 = (const float4*)b1;
#pragma unroll
  for (int j = 0; j < 8; ++j) {
    float4 a[4];
#pragma unroll
    for (int f4 = 0; f4 < 4; ++f4)
      a[f4] = wave_reduce4(make_float4(acc[j][f4 * 4], acc[j][f4 * 4 + 1],
                                       acc[j][f4 * 4 + 2], acc[j][f4 * 4 + 3]));
    if (lane == 0 && vr[j]) {
      const int r = r0 + j;
      const float d = dinv[r];
      float4* o = (float4*)(h1s + (size_t)r * HID);
#pragma unroll
      for (int f4 = 0; f4 < 4; ++f4) {
        const float4 bb = b14[f4];
        o[f4] = make_float4(d * (a[f4].x + bb.x), d * (a[f4].y + bb.y),
                            d * (a[f4].z + bb.z), d * (a[f4].w + bb.w));
      }
    }
  }
}

// Fused gather-1 + gemm2: one wave per node (16 feats x 4 edge-groups).
__global__ __launch_bounds__(BLK) void k_gather1g2(const int* __restrict__ rows,
                                                   const int* __restrict__ start,
                                                   const int* __restrict__ cnt,
                                                   const float* __restrict__ dinv,
                                                   const float* __restrict__ h1s,
                                                   const float* __restrict__ W2,
                                                   const float* __restrict__ b2,
                                                   float* __restrict__ h2s, int n) {
  __shared__ float w2s[HID * NCLS];
  __shared__ float b2s[NCLS];
  if (threadIdx.x < HID * NCLS) w2s[threadIdx.x] = W2[threadIdx.x];
  if (threadIdx.x < NCLS) b2s[threadIdx.x] = b2[threadIdx.x];
  __syncthreads();
  const int node = blockIdx.x * 4 + (threadIdx.x >> 6);
  const int lane = threadIdx.x & 63;
  const int f = lane & 15;   // feature
  const int g = lane >> 4;   // edge subgroup
  if (node >= n) return;
  const float dc = dinv[node];
  float acc = (g == 0) ? h1s[(size_t)node * HID + f] : 0.0f;  // self loop
  const int m = cnt[node];
  const int* bp = rows + start[node];
  int q = g;
  for (; q + 4 < m; q += 8) {
    const int r0 = bp[q], r1 = bp[q + 4];
    acc += h1s[(size_t)r0 * HID + f];
    acc += h1s[(size_t)r1 * HID + f];
  }
  if (q < m) acc += h1s[(size_t)bp[q] * HID + f];
  acc += __shfl_xor(acc, 16);
  acc += __shfl_xor(acc, 32);
  acc = fmaxf(dc * acc, 0.0f);  // normalize + relu
  float sj[NCLS];
#pragma unroll
  for (int j = 0; j < NCLS; ++j) sj[j] = acc * w2s[f * NCLS + j];
#pragma unroll
  for (int off = 1; off < 16; off <<= 1)
#pragma unroll
    for (int j = 0; j < NCLS; ++j) sj[j] += __shfl_xor(sj[j], off);
  if (g == 0 && f < NCLS) {
    float v = sj[0];
#pragma unroll
    for (int j = 1; j < NCLS; ++j) if (f == j) v = sj[j];
    h2s[(size_t)node * NCLS + f] = dc * (v + b2s[f]);
  }
}

// gather-2 + log_softmax: one wave per node (8 feat-lanes x 8 edge-groups)
__global__ __launch_bounds__(BLK) void k_gather2(const int* __restrict__ rows,
                                                 const int* __restrict__ start,
                                                 const int* __restrict__ cnt,
                                                 const float* __restrict__ dinv,
                                                 const float* __restrict__ h2s,
                                                 float* __restrict__ out, int n) {
  const int node = blockIdx.x * 4 + (threadIdx.x >> 6);
  const int lane = threadIdx.x & 63;
  const int f = lane & 7;    // feature (f<7 active)
  const int g = lane >> 3;   // edge subgroup
  if (node >= n) return;
  const float dc = dinv[node];
  float acc = (g == 0) ? h2s[(size_t)node * NCLS + f] : 0.0f;  // self loop
  const int m = cnt[node];
  const int* bp = rows + start[node];
  int q = g;
  for (; q + 8 < m; q += 16) {
    const int r0 = bp[q], r1 = bp[q + 8];
    acc += h2s[(size_t)r0 * NCLS + f];
    acc += h2s[(size_t)r1 * NCLS + f];
  }
  if (q < m) acc += h2s[(size_t)bp[q] * NCLS + f];
  acc += __shfl_xor(acc, 8);
  acc += __shfl_xor(acc, 16);
  acc += __shfl_xor(acc, 32);
  const bool act = f < NCLS;
  const float t = fmaxf(dc * acc, 0.0f);  // normalize + relu
  float tm = act ? t : -1e30f;
#pragma unroll
  for (int off = 1; off < 8; off <<= 1) tm = fmaxf(tm, __shfl_xor(tm, off, 8));
  float se = act ? __expf(t - tm) : 0.0f;
#pragma unroll
  for (int off = 1; off < 8; off <<= 1) se += __shfl_xor(se, off, 8);
  const float lse = tm + __logf(se);
  if (g == 0 && act) out[(size_t)node * NCLS + f] = t - lse;
}

extern "C" void kernel_launch(void* const* d_in, const int* in_sizes, int n_in,
                              void* d_out, int out_size, void* d_ws, size_t ws_size,
                              hipStream_t stream) {
  const float* x  = (const float*)d_in[0];
  const float* W1 = (const float*)d_in[1];
  const float* b1 = (const float*)d_in[2];
  const float* W2 = (const float*)d_in[3];
  const float* b2 = (const float*)d_in[4];
  const int*   ei = (const int*)d_in[5];

  const int n  = in_sizes[0] / K_IN;       // 100000
  const int nE = in_sizes[5] / 2;          // 3200000
  const int* row = ei;                     // edge_index[0] (source)
  const int* col = ei + nE;                // edge_index[1] (target)

  // workspace layout, 16B-aligned blocks
  char* w = (char*)d_ws;
  size_t off = 0;
  auto alloc = [&](size_t elems) {
    void* p = w + off;
    off += ((elems * 4 + 15) & ~(size_t)15);
    return p;
  };
  int*   cnt    = (int*)alloc(n);
  int*   start  = (int*)alloc(n);
  float* dinv   = (float*)alloc(n);
  float* h1s    = (float*)alloc((size_t)n * HID);
  float* h2s    = (float*)alloc((size_t)n * NCLS + 16);  // +pad for f==7 reads
  int*   gHist  = (int*)alloc((size_t)NB * NBLKA);
  int*   bTot   = (int*)alloc(NB);
  int*   sorted = (int*)alloc(nE);
  int*   rows   = (int*)alloc(nE);

  const int gG1 = (n + 31) / 32;          // gemm1: 32 rows/block (8/wave)
  const int gWN = (n + 3) / 4;            // wave-per-node kernels: 4 nodes/block

  // atomic-free CSR build
  k_histA<<<NBLKA, 256, 0, stream>>>(col, gHist, nE);
  k_scanA<<<NB, 256, 0, stream>>>(gHist, bTot);
  k_placeA<<<NBLKA, 256, 0, stream>>>(row, col, gHist, bTot, sorted, nE);
  k_bucketB<<<NB, 256, 0, stream>>>(sorted, bTot, cnt, start, dinv, rows, n);

  // layer 1 (+ fused layer-2 linear)
  k_gemm1<<<gG1, BLK, 0, stream>>>(x, W1, b1, dinv, h1s, n);
  k_gather1g2<<<gWN, BLK, 0, stream>>>(rows, start, cnt, dinv, h1s, W2, b2, h2s, n);

  // layer 2 aggregation + log_softmax
  k_gather2<<<gWN, BLK, 0, stream>>>(rows, start, cnt, dinv, h2s, (float*)d_out, n);
}

// Round 21
// 413.212 us; speedup vs baseline: 1.7189x; 1.7189x over previous
//
#include <hip/hip_runtime.h>
#include <math.h>

constexpr int K_IN  = 1433;
constexpr int HID   = 16;
constexpr int NCLS  = 7;
constexpr int BLK   = 256;
constexpr int NB    = 256;   // coarse buckets: bucket = col >> 9
constexpr int NBLKA = 1024;  // pass-A blocks

__device__ inline float4 wave_reduce4(float4 v) {
#pragma unroll
  for (int off = 32; off > 0; off >>= 1) {
    v.x += __shfl_xor(v.x, off);
    v.y += __shfl_xor(v.y, off);
    v.z += __shfl_xor(v.z, off);
    v.w += __shfl_xor(v.w, off);
  }
  return v;
}

// exclusive scan over 256 values held one-per-thread (256-thread block)
__device__ inline int block_excl_scan256(int v, int* wsum) {
  const int lane = threadIdx.x & 63, wid = threadIdx.x >> 6;
  int s = v;
#pragma unroll
  for (int off = 1; off < 64; off <<= 1) {
    int t = __shfl_up(s, off);
    if (lane >= off) s += t;
  }
  if (lane == 63) wsum[wid] = s;
  __syncthreads();
  int woff = 0;
#pragma unroll
  for (int k = 0; k < 4; ++k) woff += (k < wid) ? wsum[k] : 0;
  return woff + s - v;
}

// ---- atomic-free CSR build (two-level LDS-histogram counting sort) -----

__global__ __launch_bounds__(256) void k_histA(const int* __restrict__ col,
                                               int* __restrict__ gHist, int nE) {
  __shared__ int h[NB];
  h[threadIdx.x] = 0;
  __syncthreads();
  const int ch = (nE + NBLKA - 1) / NBLKA;
  const int e0 = blockIdx.x * ch;
  const int e1 = min(e0 + ch, nE);
  for (int e = e0 + threadIdx.x; e < e1; e += 256) atomicAdd(&h[col[e] >> 9], 1);
  __syncthreads();
  gHist[threadIdx.x * NBLKA + blockIdx.x] = h[threadIdx.x];  // bucket-major
}

__global__ __launch_bounds__(256) void k_scanA(int* __restrict__ gHist,
                                               int* __restrict__ bTot) {
  __shared__ int wsum[4];
  const int b = blockIdx.x, t = threadIdx.x;
  int4* p = (int4*)(gHist + (size_t)b * NBLKA);
  int4 c = p[t];
  const int tsum = c.x + c.y + c.z + c.w;
  const int base = block_excl_scan256(tsum, wsum);
  int4 o; o.x = base; o.y = base + c.x; o.z = o.y + c.y; o.w = o.z + c.z;
  p[t] = o;
  if (t == 255) bTot[b] = base + tsum;
}

__global__ __launch_bounds__(256) void k_placeA(const int* __restrict__ row,
                                                const int* __restrict__ col,
                                                const int* __restrict__ gHist,
                                                const int* __restrict__ bTot,
                                                int* __restrict__ sorted, int nE) {
  __shared__ int cur[NB];
  __shared__ int wsum[4];
  const int t = threadIdx.x;
  const int excl = block_excl_scan256(bTot[t], wsum);   // bBase on the fly
  cur[t] = excl + gHist[t * NBLKA + blockIdx.x];
  __syncthreads();
  const int ch = (nE + NBLKA - 1) / NBLKA;
  const int e0 = blockIdx.x * ch;
  const int e1 = min(e0 + ch, nE);
  for (int e = e0 + t; e < e1; e += 256) {
    const int c = col[e];
    const int p = atomicAdd(&cur[c >> 9], 1);           // LDS atomic
    sorted[p] = ((c & 511) << 17) | row[e];             // 26-bit pack
  }
}

__global__ __launch_bounds__(256) void k_bucketB(const int* __restrict__ sorted,
                                                 const int* __restrict__ bTot,
                                                 int* __restrict__ cnt,
                                                 int* __restrict__ start,
                                                 float* __restrict__ dinv,
                                                 int* __restrict__ rows, int n) {
  __shared__ int h[512];
  __shared__ int ls[512];
  __shared__ int sBase[NB];
  __shared__ int wsum[4];
  const int b = blockIdx.x, t = threadIdx.x;
  const int lane = t & 63, wid = t >> 6;
  h[t] = 0; h[t + 256] = 0;
  sBase[t] = block_excl_scan256(bTot[t], wsum);         // bBase on the fly
  __syncthreads();
  const int s0 = sBase[b];
  const int s1 = (b < 255) ? sBase[b + 1] : s0 + bTot[b];
  for (int e = s0 + t; e < s1; e += 256) atomicAdd(&h[(sorted[e] >> 17) & 511], 1);
  __syncthreads();
  const int c0 = h[2 * t], c1 = h[2 * t + 1];
  const int tsum = c0 + c1;
  int s = tsum;
#pragma unroll
  for (int off = 1; off < 64; off <<= 1) { int v = __shfl_up(s, off); if (lane >= off) s += v; }
  if (lane == 63) wsum[wid] = s;
  __syncthreads();
  int woff = 0;
#pragma unroll
  for (int k = 0; k < 4; ++k) woff += (k < wid) ? wsum[k] : 0;
  const int base = woff + s - tsum;
  ls[2 * t] = base;
  ls[2 * t + 1] = base + c0;
  const int gc0 = b * 512 + 2 * t;
  if (gc0 < n) {
    cnt[gc0] = c0; start[gc0] = s0 + base;
    dinv[gc0] = rsqrtf((float)(c0 + 1));
  }
  if (gc0 + 1 < n) {
    cnt[gc0 + 1] = c1; start[gc0 + 1] = s0 + base + c0;
    dinv[gc0 + 1] = rsqrtf((float)(c1 + 1));
  }
  __syncthreads();
  for (int e = s0 + t; e < s1; e += 256) {
    const int rc = sorted[e];
    const int p = atomicAdd(&ls[(rc >> 17) & 511], 1);  // LDS cursor
    rows[s0 + p] = rc & 0x1FFFF;
  }
}

// ---- layer compute -----------------------------------------------------

// h1s = dinv * (x @ W1 + b1). v10: register-W, 8 ROWS/WAVE, no LDS/barriers.
// W L2 traffic halved vs v8 (amortized over 8 rows); 256-cyc FMA burst per
// load-wait covers L2 latency at 2 waves/SIMD. Straight-line, static acc.
__global__ __launch_bounds__(BLK) void k_gemm1(const float* __restrict__ x,
                                               const float* __restrict__ W1,
                                               const float* __restrict__ b1,
                                               const float* __restrict__ dinv,
                                               float* __restrict__ h1s, int n) {
  const int lane = threadIdx.x & 63;
  const int wave = threadIdx.x >> 6;
  const int r0 = blockIdx.x * 32 + wave * 8;
  bool vr[8];
  const float* xr[8];
#pragma unroll
  for (int j = 0; j < 8; ++j) {
    vr[j] = (r0 + j) < n;
    xr[j] = x + (size_t)(vr[j] ? r0 + j : 0) * K_IN;   // clamp, masked below
  }
  float acc[8][HID] = {};

  constexpr int NSTEP = (K_IN + 63) / 64;   // 23 (22 full + 1 tail)
#pragma unroll 2
  for (int s = 0; s < NSTEP - 1; ++s) {     // full steps: k always < K_IN
    const int k = s * 64 + lane;
    const float4* wp = (const float4*)(W1 + (size_t)k * HID);
    const float4 ww[4] = {wp[0], wp[1], wp[2], wp[3]};
    float xv[8];
#pragma unroll
    for (int j = 0; j < 8; ++j) xv[j] = vr[j] ? xr[j][k] : 0.0f;
#pragma unroll
    for (int j = 0; j < 8; ++j)
#pragma unroll
      for (int f4 = 0; f4 < 4; ++f4) {
        acc[j][f4 * 4 + 0] = fmaf(xv[j], ww[f4].x, acc[j][f4 * 4 + 0]);
        acc[j][f4 * 4 + 1] = fmaf(xv[j], ww[f4].y, acc[j][f4 * 4 + 1]);
        acc[j][f4 * 4 + 2] = fmaf(xv[j], ww[f4].z, acc[j][f4 * 4 + 2]);
        acc[j][f4 * 4 + 3] = fmaf(xv[j], ww[f4].w, acc[j][f4 * 4 + 3]);
      }
  }
  {                                         // tail step: k = 1408 + lane
    const int k = (NSTEP - 1) * 64 + lane;
    if (k < K_IN) {
      const float4* wp = (const float4*)(W1 + (size_t)k * HID);
      const float4 ww[4] = {wp[0], wp[1], wp[2], wp[3]};
      float xv[8];
#pragma unroll
      for (int j = 0; j < 8; ++j) xv[j] = vr[j] ? xr[j][k] : 0.0f;
#pragma unroll
      for (int j = 0; j < 8; ++j)
#pragma unroll
        for (int f4 = 0; f4 < 4; ++f4) {
          acc[j][f4 * 4 + 0] = fmaf(xv[j], ww[f4].x, acc[j][f4 * 4 + 0]);
          acc[j][f4 * 4 + 1] = fmaf(xv[j], ww[f4].y, acc[j][f4 * 4 + 1]);
          acc[j][f4 * 4 + 2] = fmaf(xv[j], ww[f4].z, acc[j][f4 * 4 + 2]);
          acc[j][f4 * 4 + 3] = fmaf(xv[j], ww[f4].w, acc[j][f4 * 4 + 3]);
        }
    }
  }

  const float4* b14 = (const float4*)b1;
#pragma unroll
  for (int j = 0; j < 8; ++j) {
    float4 a[4];
#pragma unroll
    for (int f4 = 0; f4 < 4; ++f4)
      a[f4] = wave_reduce4(make_float4(acc[j][f4 * 4], acc[j][f4 * 4 + 1],
                                       acc[j][f4 * 4 + 2], acc[j][f4 * 4 + 3]));
    if (lane == 0 && vr[j]) {
      const int r = r0 + j;
      const float d = dinv[r];
      float4* o = (float4*)(h1s + (size_t)r * HID);
#pragma unroll
      for (int f4 = 0; f4 < 4; ++f4) {
        const float4 bb = b14[f4];
        o[f4] = make_float4(d * (a[f4].x + bb.x), d * (a[f4].y + bb.y),
                            d * (a[f4].z + bb.z), d * (a[f4].w + bb.w));
      }
    }
  }
}

// Fused gather-1 + gemm2: one wave per node (16 feats x 4 edge-groups).
__global__ __launch_bounds__(BLK) void k_gather1g2(const int* __restrict__ rows,
                                                   const int* __restrict__ start,
                                                   const int* __restrict__ cnt,
                                                   const float* __restrict__ dinv,
                                                   const float* __restrict__ h1s,
                                                   const float* __restrict__ W2,
                                                   const float* __restrict__ b2,
                                                   float* __restrict__ h2s, int n) {
  __shared__ float w2s[HID * NCLS];
  __shared__ float b2s[NCLS];
  if (threadIdx.x < HID * NCLS) w2s[threadIdx.x] = W2[threadIdx.x];
  if (threadIdx.x < NCLS) b2s[threadIdx.x] = b2[threadIdx.x];
  __syncthreads();
  const int node = blockIdx.x * 4 + (threadIdx.x >> 6);
  const int lane = threadIdx.x & 63;
  const int f = lane & 15;   // feature
  const int g = lane >> 4;   // edge subgroup
  if (node >= n) return;
  const float dc = dinv[node];
  float acc = (g == 0) ? h1s[(size_t)node * HID + f] : 0.0f;  // self loop
  const int m = cnt[node];
  const int* bp = rows + start[node];
  int q = g;
  for (; q + 4 < m; q += 8) {
    const int r0 = bp[q], r1 = bp[q + 4];
    acc += h1s[(size_t)r0 * HID + f];
    acc += h1s[(size_t)r1 * HID + f];
  }
  if (q < m) acc += h1s[(size_t)bp[q] * HID + f];
  acc += __shfl_xor(acc, 16);
  acc += __shfl_xor(acc, 32);
  acc = fmaxf(dc * acc, 0.0f);  // normalize + relu
  float sj[NCLS];
#pragma unroll
  for (int j = 0; j < NCLS; ++j) sj[j] = acc * w2s[f * NCLS + j];
#pragma unroll
  for (int off = 1; off < 16; off <<= 1)
#pragma unroll
    for (int j = 0; j < NCLS; ++j) sj[j] += __shfl_xor(sj[j], off);
  if (g == 0 && f < NCLS) {
    float v = sj[0];
#pragma unroll
    for (int j = 1; j < NCLS; ++j) if (f == j) v = sj[j];
    h2s[(size_t)node * NCLS + f] = dc * (v + b2s[f]);
  }
}

// gather-2 + log_softmax: one wave per node (8 feat-lanes x 8 edge-groups)
__global__ __launch_bounds__(BLK) void k_gather2(const int* __restrict__ rows,
                                                 const int* __restrict__ start,
                                                 const int* __restrict__ cnt,
                                                 const float* __restrict__ dinv,
                                                 const float* __restrict__ h2s,
                                                 float* __restrict__ out, int n) {
  const int node = blockIdx.x * 4 + (threadIdx.x >> 6);
  const int lane = threadIdx.x & 63;
  const int f = lane & 7;    // feature (f<7 active)
  const int g = lane >> 3;   // edge subgroup
  if (node >= n) return;
  const float dc = dinv[node];
  float acc = (g == 0) ? h2s[(size_t)node * NCLS + f] : 0.0f;  // self loop
  const int m = cnt[node];
  const int* bp = rows + start[node];
  int q = g;
  for (; q + 8 < m; q += 16) {
    const int r0 = bp[q], r1 = bp[q + 8];
    acc += h2s[(size_t)r0 * NCLS + f];
    acc += h2s[(size_t)r1 * NCLS + f];
  }
  if (q < m) acc += h2s[(size_t)bp[q] * NCLS + f];
  acc += __shfl_xor(acc, 8);
  acc += __shfl_xor(acc, 16);
  acc += __shfl_xor(acc, 32);
  const bool act = f < NCLS;
  const float t = fmaxf(dc * acc, 0.0f);  // normalize + relu
  float tm = act ? t : -1e30f;
#pragma unroll
  for (int off = 1; off < 8; off <<= 1) tm = fmaxf(tm, __shfl_xor(tm, off, 8));
  float se = act ? __expf(t - tm) : 0.0f;
#pragma unroll
  for (int off = 1; off < 8; off <<= 1) se += __shfl_xor(se, off, 8);
  const float lse = tm + __logf(se);
  if (g == 0 && act) out[(size_t)node * NCLS + f] = t - lse;
}

extern "C" void kernel_launch(void* const* d_in, const int* in_sizes, int n_in,
                              void* d_out, int out_size, void* d_ws, size_t ws_size,
                              hipStream_t stream) {
  const float* x  = (const float*)d_in[0];
  const float* W1 = (const float*)d_in[1];
  const float* b1 = (const float*)d_in[2];
  const float* W2 = (const float*)d_in[3];
  const float* b2 = (const float*)d_in[4];
  const int*   ei = (const int*)d_in[5];

  const int n  = in_sizes[0] / K_IN;       // 100000
  const int nE = in_sizes[5] / 2;          // 3200000
  const int* row = ei;                     // edge_index[0] (source)
  const int* col = ei + nE;                // edge_index[1] (target)

  // workspace layout, 16B-aligned blocks
  char* w = (char*)d_ws;
  size_t off = 0;
  auto alloc = [&](size_t elems) {
    void* p = w + off;
    off += ((elems * 4 + 15) & ~(size_t)15);
    return p;
  };
  int*   cnt    = (int*)alloc(n);
  int*   start  = (int*)alloc(n);
  float* dinv   = (float*)alloc(n);
  float* h1s    = (float*)alloc((size_t)n * HID);
  float* h2s    = (float*)alloc((size_t)n * NCLS + 16);  // +pad for f==7 reads
  int*   gHist  = (int*)alloc((size_t)NB * NBLKA);
  int*   bTot   = (int*)alloc(NB);
  int*   sorted = (int*)alloc(nE);
  int*   rows   = (int*)alloc(nE);

  const int gG1 = (n + 31) / 32;          // gemm1: 32 rows/block (8/wave)
  const int gWN = (n + 3) / 4;            // wave-per-node kernels: 4 nodes/block

  // atomic-free CSR build
  k_histA<<<NBLKA, 256, 0, stream>>>(col, gHist, nE);
  k_scanA<<<NB, 256, 0, stream>>>(gHist, bTot);
  k_placeA<<<NBLKA, 256, 0, stream>>>(row, col, gHist, bTot, sorted, nE);
  k_bucketB<<<NB, 256, 0, stream>>>(sorted, bTot, cnt, start, dinv, rows, n);

  // layer 1 (+ fused layer-2 linear)
  k_gemm1<<<gG1, BLK, 0, stream>>>(x, W1, b1, dinv, h1s, n);
  k_gather1g2<<<gWN, BLK, 0, stream>>>(rows, start, cnt, dinv, h1s, W2, b2, h2s, n);

  // layer 2 aggregation + log_softmax
  k_gather2<<<gWN, BLK, 0, stream>>>(rows, start, cnt, dinv, h2s, (float*)d_out, n);
}